// Round 9
// baseline (15.049 us; speedup 1.0000x reference)
//
#include <hip/hip_runtime.h>
#include <math.h>

// Closed form (Heisenberg-picture Pauli propagation through the 6-gate circuit):
//   z1 = cos(b + pi*phi0)
//   z0 = cos(a+d) * cos(pi*phi1) * z1
// where a=w[0,0] (RX low), b=w[0,1] (RY high), d=w[1,1] (RX high).
// w[1,0] (RZ) provably does not affect Z-expectations.
//
// x: (B,128,128) f32; out: (B,64,64,2) f32.
// Pixel (p,q): r=min(2p+1,126), c=min(2q+1,126), phi0=x[r,c], phi1=x[r,c+1].
//
// Wave-dense, MLP=8 mapping: each wave covers 16 output rows via eight
// independent fully-dense 1 KB loads (lanes 0-31 = one odd row's 512 B,
// lanes 32-63 = the next row), all issued before compute, then eight dense
// 1 KB stores (regular, through L2 — A/B vs nontemporal).
// Thread = 16 pixels: 8 loads, 8 shuffles, 8 stores.

typedef float vfloat4 __attribute__((ext_vector_type(4)));

__device__ __forceinline__ vfloat4 qpair(vfloat4 v, float nx, int l,
                                         float wb, float R) {
    const float PI_F = 3.14159265358979f;
    // pixel q=2l:   c=4l+1 -> (v.y, v.z)
    float z1_0 = __cosf(fmaf(PI_F, v.y, wb));
    float z0_0 = R * __cosf(PI_F * v.z) * z1_0;
    // pixel q=2l+1: c=4l+3 -> (v.w, nx); l==31: c=127 clamps to 126 -> (v.z, v.w)
    float e0 = (l == 31) ? v.z : v.w;
    float e1 = (l == 31) ? v.w : nx;
    float z1_1 = __cosf(fmaf(PI_F, e0, wb));
    float z0_1 = R * __cosf(PI_F * e1) * z1_1;
    vfloat4 o = { z0_0, z1_0, z0_1, z1_1 };
    return o;
}

__global__ __launch_bounds__(256) void qconv_main(const float* __restrict__ x,
                                                  const float* __restrict__ w,
                                                  vfloat4* __restrict__ out,
                                                  int nwaves) {
    int tid  = blockIdx.x * 256 + threadIdx.x;
    int wid  = tid >> 6;
    if (wid >= nwaves) return;
    int lane = threadIdx.x & 63;
    int l    = lane & 31;          // float4 index within the 512 B row
    int half = lane >> 5;          // which row of each pair this half-wave covers

    // This wave's 16 output rows: h_k = wid*16 + 2k + half, k=0..7 (h = img*64 + p)
    int hbase = wid * 16 + half;

    vfloat4 v[8];
#pragma unroll
    for (int k = 0; k < 8; ++k) {
        int h = hbase + 2 * k;
        int p = h & 63, img = h >> 6;
        int r = 2 * p + 1; if (r > 126) r = 126;
        v[k] = ((const vfloat4*)(x + ((size_t)(img * 128 + r)) * 128))[l];
    }

    float wb_ = w[1];
    float R   = __cosf(w[0] + w[3]);

    float n[8];
#pragma unroll
    for (int k = 0; k < 8; ++k) n[k] = __shfl_down(v[k].x, 1);

#pragma unroll
    for (int k = 0; k < 8; ++k) {
        vfloat4 o = qpair(v[k], n[k], l, wb_, R);
        out[(hbase + 2 * k) * 32 + l] = o;
    }
}

extern "C" void kernel_launch(void* const* d_in, const int* in_sizes, int n_in,
                              void* d_out, int out_size, void* d_ws, size_t ws_size,
                              hipStream_t stream) {
    const float* x = (const float*)d_in[0];
    const float* w = (const float*)d_in[1];
    vfloat4* out = (vfloat4*)d_out;

    int B = in_sizes[0] / (128 * 128);
    int totalRows = B * 64;
    int nwaves = totalRows / 16;         // each wave covers 16 output rows
    int nthreads = nwaves * 64;

    qconv_main<<<(nthreads + 255) / 256, 256, 0, stream>>>(x, w, out, nwaves);
}

// Round 10
// 13.804 us; speedup vs baseline: 1.0903x; 1.0903x over previous
//
#include <hip/hip_runtime.h>
#include <math.h>

// Closed form (Heisenberg-picture Pauli propagation through the 6-gate circuit):
//   z1 = cos(b + pi*phi0)
//   z0 = cos(a+d) * cos(pi*phi1) * z1
// where a=w[0,0] (RX low), b=w[0,1] (RY high), d=w[1,1] (RX high).
// w[1,0] (RZ) provably does not affect Z-expectations.
//
// x: (B,128,128) f32; out: (B,64,64,2) f32.
// Pixel (p,q): r=min(2p+1,126), c=min(2q+1,126), phi0=x[r,c], phi1=x[r,c+1].
//
// CHAMPION CONFIG (R8, 13.6 us): wave-dense MLP=4 + nontemporal stores.
// Each wave covers 8 output rows via four independent fully-dense 1 KB loads
// (lanes 0-31 = one odd row's 512 B, lanes 32-63 = the next row), all issued
// before compute, then four dense 1 KB NT stores.
// R9 post-mortem: MLP=8 + regular stores regressed to 15.0 us — NT streaming
// stores beat L2-allocating stores for write-once data; MLP=4 is sufficient.

typedef float vfloat4 __attribute__((ext_vector_type(4)));

__device__ __forceinline__ vfloat4 qpair(vfloat4 v, float nx, int l,
                                         float wb, float R) {
    const float PI_F = 3.14159265358979f;
    // pixel q=2l:   c=4l+1 -> (v.y, v.z)
    float z1_0 = __cosf(fmaf(PI_F, v.y, wb));
    float z0_0 = R * __cosf(PI_F * v.z) * z1_0;
    // pixel q=2l+1: c=4l+3 -> (v.w, nx); l==31: c=127 clamps to 126 -> (v.z, v.w)
    float e0 = (l == 31) ? v.z : v.w;
    float e1 = (l == 31) ? v.w : nx;
    float z1_1 = __cosf(fmaf(PI_F, e0, wb));
    float z0_1 = R * __cosf(PI_F * e1) * z1_1;
    vfloat4 o = { z0_0, z1_0, z0_1, z1_1 };
    return o;
}

__global__ __launch_bounds__(256) void qconv_main(const float* __restrict__ x,
                                                  const float* __restrict__ w,
                                                  vfloat4* __restrict__ out,
                                                  int nwaves) {
    int tid  = blockIdx.x * 256 + threadIdx.x;
    int wid  = tid >> 6;
    if (wid >= nwaves) return;
    int lane = threadIdx.x & 63;
    int l    = lane & 31;          // float4 index within the 512 B row
    int half = lane >> 5;          // which row of each pair this half-wave covers

    // This wave's 8 output rows: h_k = wid*8 + 2k + half, k=0..3 (h = img*64 + p)
    int hbase = wid * 8 + half;

    const vfloat4* rows[4];
#pragma unroll
    for (int k = 0; k < 4; ++k) {
        int h = hbase + 2 * k;
        int p = h & 63, img = h >> 6;
        int r = 2 * p + 1; if (r > 126) r = 126;
        rows[k] = (const vfloat4*)(x + ((size_t)(img * 128 + r)) * 128);
    }

    // Issue all four loads before any dependent use (MLP=4).
    vfloat4 v0 = rows[0][l];
    vfloat4 v1 = rows[1][l];
    vfloat4 v2 = rows[2][l];
    vfloat4 v3 = rows[3][l];

    float wb_ = w[1];
    float R   = __cosf(w[0] + w[3]);

    float n0 = __shfl_down(v0.x, 1);   // elem 4l+4 (unused at l==31)
    float n1 = __shfl_down(v1.x, 1);
    float n2 = __shfl_down(v2.x, 1);
    float n3 = __shfl_down(v3.x, 1);

    vfloat4 o0 = qpair(v0, n0, l, wb_, R);
    vfloat4 o1 = qpair(v1, n1, l, wb_, R);
    vfloat4 o2 = qpair(v2, n2, l, wb_, R);
    vfloat4 o3 = qpair(v3, n3, l, wb_, R);

    __builtin_nontemporal_store(o0, &out[(hbase + 0) * 32 + l]);
    __builtin_nontemporal_store(o1, &out[(hbase + 2) * 32 + l]);
    __builtin_nontemporal_store(o2, &out[(hbase + 4) * 32 + l]);
    __builtin_nontemporal_store(o3, &out[(hbase + 6) * 32 + l]);
}

extern "C" void kernel_launch(void* const* d_in, const int* in_sizes, int n_in,
                              void* d_out, int out_size, void* d_ws, size_t ws_size,
                              hipStream_t stream) {
    const float* x = (const float*)d_in[0];
    const float* w = (const float*)d_in[1];
    vfloat4* out = (vfloat4*)d_out;

    int B = in_sizes[0] / (128 * 128);
    int totalRows = B * 64;
    int nwaves = totalRows / 8;          // each wave covers 8 output rows
    int nthreads = nwaves * 64;

    qconv_main<<<(nthreads + 255) / 256, 256, 0, stream>>>(x, w, out, nwaves);
}